// Round 2
// baseline (457.134 us; speedup 1.0000x reference)
//
#include <hip/hip_runtime.h>
#include <hip/hip_bf16.h>

typedef __attribute__((ext_vector_type(4))) float floatx4;
typedef __attribute__((ext_vector_type(8))) short shortx8;
typedef __attribute__((ext_vector_type(4))) short shortx4;
typedef _Float16 half_t;

#define MFMA_BF16(A,B,C) __builtin_amdgcn_mfma_f32_16x16x32_bf16((A),(B),(C),0,0,0)
#define NEG_INF (-__builtin_inff())
#define GLOBAL_AS __attribute__((address_space(1)))
#define LDS_AS __attribute__((address_space(3)))

static __device__ __forceinline__ unsigned short f2b(float f) {
    union { float f; unsigned u; } v; v.f = f;
    unsigned r = v.u + 0x7FFFu + ((v.u >> 16) & 1u);   // RNE fp32 -> bf16
    return (unsigned short)(r >> 16);
}
static __device__ __forceinline__ float EXP2F(float x) { return __builtin_amdgcn_exp2f(x); }

#define NSPLIT 16
#define NTILES 257

// ---------------- weights: transpose + bf16 ----------------
__global__ __launch_bounds__(256) void wtrans_kernel(
    const float* __restrict__ wq, const float* __restrict__ wk,
    const float* __restrict__ wv, const float* __restrict__ wo,
    unsigned short* __restrict__ wqt, unsigned short* __restrict__ wkt,
    unsigned short* __restrict__ wvt, unsigned short* __restrict__ wot)
{
    int gid = blockIdx.x * 256 + threadIdx.x;
    if (gid < 65536) {
        int n = gid >> 8, k = gid & 255;
        wqt[gid] = f2b(wq[k * 256 + n]);
    } else if (gid < 81920) {
        int j = gid - 65536, n = j >> 6, k = j & 63;
        wkt[j] = f2b(wk[k * 256 + n]);
    } else if (gid < 98304) {
        int j = gid - 81920, n = j >> 6, k = j & 63;
        wvt[j] = f2b(wv[k * 256 + n]);
    } else {
        int j = gid - 98304, n = j >> 8, k = j & 255;
        wot[j] = f2b(wo[k * 256 + n]);
    }
}

// ---------------- q projection + RoPE + scale (64 rows x 64 cols per block) ----------------
__global__ __launch_bounds__(256) void qproj_kernel(
    const float* __restrict__ query, const unsigned short* __restrict__ wqt,
    const float* __restrict__ bq, const float* __restrict__ cosb,
    const float* __restrict__ sinb, unsigned short* __restrict__ qr)
{
    const int tid = threadIdx.x;
    const int wave = tid >> 6, lane = tid & 63;
    const int c = lane & 15, quad = lane >> 4;
    const int m0 = blockIdx.x * 64;
    const int n0 = blockIdx.y * 64;

    shortx8 aA[8];
    {
        const int mrow = m0 + wave * 16 + c;
        #pragma unroll
        for (int ks = 0; ks < 8; ks++) {
            const float* p = query + mrow * 256 + ks * 32 + quad * 8;
            floatx4 f0 = *(const floatx4*)p;
            floatx4 f1 = *(const floatx4*)(p + 4);
            shortx8 a;
            #pragma unroll
            for (int j = 0; j < 4; j++) { a[j] = (short)f2b(f0[j]); a[j + 4] = (short)f2b(f1[j]); }
            aA[ks] = a;
        }
    }
    floatx4 acc[4];
    #pragma unroll
    for (int nt = 0; nt < 4; nt++) { acc[nt][0]=0.f; acc[nt][1]=0.f; acc[nt][2]=0.f; acc[nt][3]=0.f; }
    #pragma unroll
    for (int nt = 0; nt < 4; nt++) {
        #pragma unroll
        for (int ks = 0; ks < 8; ks++) {
            shortx8 b = *(const shortx8*)(wqt + (n0 + nt * 16 + c) * 256 + ks * 32 + quad * 8);
            acc[nt] = MFMA_BF16(aA[ks], b, acc[nt]);
        }
    }
    const float sc = 0.09016844005556021f;  // (1/16) * log2(e)
    #pragma unroll
    for (int nt = 0; nt < 4; nt++) {
        const int col = n0 + nt * 16 + c;
        #pragma unroll
        for (int r = 0; r < 4; r++) {
            const int row = m0 + wave * 16 + quad * 4 + r;
            float v = acc[nt][r] + bq[col];
            float partner = __shfl_xor(v, 1);
            float cv = cosb[row * 256 + col];
            float sn = sinb[row * 256 + col];
            float rot = (col & 1) ? partner : -partner;
            qr[row * 256 + col] = f2b((v * cv + rot * sn) * sc);
        }
    }
}

// ---------------- fused k/v projection ----------------
__global__ __launch_bounds__(256) void kvproj_kernel(
    const float* __restrict__ key, const float* __restrict__ value,
    const unsigned short* __restrict__ wkt, const unsigned short* __restrict__ wvt,
    const float* __restrict__ bk, const float* __restrict__ bv,
    const float* __restrict__ cosb, const float* __restrict__ sinb,
    const int* __restrict__ nkx, unsigned short* __restrict__ krw,
    unsigned short* __restrict__ vtg)
{
    __shared__ unsigned short tbuf[256 * 72];
    const int tid = threadIdx.x;
    const int wave = tid >> 6, lane = tid & 63;
    const int c = lane & 15, quad = lane >> 4;
    const int m0 = blockIdx.x * 64;
    const int isv = blockIdx.y;

    const float* src = isv ? value : key;
    const unsigned short* wt = isv ? wvt : wkt;
    const float* bias = isv ? bv : bk;

    shortx8 aA[2];
    {
        const int mrow = m0 + wave * 16 + c;
        #pragma unroll
        for (int ks = 0; ks < 2; ks++) {
            const float* p = src + mrow * 64 + ks * 32 + quad * 8;
            floatx4 f0 = *(const floatx4*)p;
            floatx4 f1 = *(const floatx4*)(p + 4);
            shortx8 a;
            #pragma unroll
            for (int j = 0; j < 4; j++) { a[j] = (short)f2b(f0[j]); a[j + 4] = (short)f2b(f1[j]); }
            aA[ks] = a;
        }
    }
    floatx4 acc[16];
    #pragma unroll
    for (int nt = 0; nt < 16; nt++) { acc[nt][0]=0.f; acc[nt][1]=0.f; acc[nt][2]=0.f; acc[nt][3]=0.f; }
    #pragma unroll
    for (int nt = 0; nt < 16; nt++) {
        #pragma unroll
        for (int ks = 0; ks < 2; ks++) {
            shortx8 b = *(const shortx8*)(wt + (nt * 16 + c) * 64 + ks * 32 + quad * 8);
            acc[nt] = MFMA_BF16(aA[ks], b, acc[nt]);
        }
    }
    if (!isv) {
        // K path: bias + partial RoPE, row-major bf16 out
        const int n_rot = 16448 - nkx[0];
        int rep = n_rot / 4096; if (rep < 1) rep = 1;
        int rc4[4];
        #pragma unroll
        for (int r = 0; r < 4; r++) {
            int row = m0 + wave * 16 + quad * 4 + r;
            rc4[r] = row / rep;
        }
        #pragma unroll
        for (int nt = 0; nt < 16; nt++) {
            const int col = nt * 16 + c;
            #pragma unroll
            for (int r = 0; r < 4; r++) {
                const int row = m0 + wave * 16 + quad * 4 + r;
                float v = acc[nt][r] + bias[col];
                float partner = __shfl_xor(v, 1);
                float outv = v;
                if (row < n_rot) {
                    float cv = cosb[rc4[r] * 256 + col];
                    float sn = sinb[rc4[r] * 256 + col];
                    float rot = (col & 1) ? partner : -partner;
                    outv = v * cv + rot * sn;
                }
                krw[row * 256 + col] = f2b(outv);
            }
        }
    } else {
        // V path: bias, transposed store vt[d][kv]
        #pragma unroll
        for (int nt = 0; nt < 16; nt++) {
            const int col = nt * 16 + c;
            #pragma unroll
            for (int r = 0; r < 4; r++) {
                const int rl = wave * 16 + quad * 4 + r;
                tbuf[col * 72 + rl] = f2b(acc[nt][r] + bias[col]);
            }
        }
        __syncthreads();
        #pragma unroll
        for (int i = 0; i < 8; i++) {
            int G = i * 256 + tid;
            int n = G >> 3, g = G & 7;
            *(floatx4*)(vtg + n * 16448 + m0 + g * 8) = *(const floatx4*)(tbuf + n * 72 + g * 8);
        }
    }
}

// ---------------- flash attention: 32 q-rows/wave, 16 splits ----------------
__global__ __launch_bounds__(256, 2) void flash_kernel(
    const unsigned short* __restrict__ qr, const unsigned short* __restrict__ kr,
    const unsigned short* __restrict__ vt, half_t* __restrict__ Opart,
    float* __restrict__ Mpart, float* __restrict__ Lpart)
{
    __shared__ unsigned short smem[40960];   // 80 KB exactly -> 2 blocks/CU
    unsigned short* kbuf = smem;             // 64 kv x 256 d, swizzled granules
    unsigned short* vbuf = smem + 16384;     // 256 d x 64 kv, swizzled granules
    unsigned short* pbuf = smem + 32768;     // per-wave 32 x 64, swizzled granules

    const int tid = threadIdx.x;
    const int wave = tid >> 6, lane = tid & 63;
    const int c = lane & 15, quad = lane >> 4;
    const int cx = c & 7;
    const int qrow0 = blockIdx.x * 128 + wave * 32;
    const int s = blockIdx.y;
    const int t0 = (s * NTILES) / NSPLIT, t1 = ((s + 1) * NTILES) / NSPLIT;
    unsigned short* pw = pbuf + wave * 2048;

    shortx8 aQ[2][8];
    #pragma unroll
    for (int u = 0; u < 2; u++)
        #pragma unroll
        for (int ks = 0; ks < 8; ks++)
            aQ[u][ks] = *(const shortx8*)(qr + (qrow0 + u * 16 + c) * 256 + ks * 32 + quad * 8);

    floatx4 o[2][16];
    #pragma unroll
    for (int u = 0; u < 2; u++)
        #pragma unroll
        for (int nt = 0; nt < 16; nt++) { o[u][nt][0]=0.f; o[u][nt][1]=0.f; o[u][nt][2]=0.f; o[u][nt][3]=0.f; }
    float m_i[2][4], l_i[2][4];
    #pragma unroll
    for (int u = 0; u < 2; u++)
        #pragma unroll
        for (int r = 0; r < 4; r++) { m_i[u][r] = NEG_INF; l_i[u][r] = 0.f; }

    for (int t = t0; t < t1; t++) {
        const int kv0 = t * 64;
        // stage K tile (32 KB) via direct-to-LDS DMA, swizzle folded into source addr
        #pragma unroll
        for (int i = 0; i < 8; i++) {
            int L = i * 256 + tid;
            int kv = L >> 5, p = L & 31;
            int g = (p & 24) | ((p & 7) ^ (kv & 7));
            __builtin_amdgcn_global_load_lds(
                (const GLOBAL_AS void*)(const void*)(kr + (kv0 + kv) * 256 + g * 8),
                (LDS_AS void*)(void*)(kbuf + (i * 256 + wave * 64) * 8), 16, 0, 0);
        }
        // stage Vt tile (32 KB)
        #pragma unroll
        for (int i = 0; i < 8; i++) {
            int L = i * 256 + tid;
            int d = L >> 3, p = L & 7;
            int g = p ^ (d & 7);
            __builtin_amdgcn_global_load_lds(
                (const GLOBAL_AS void*)(const void*)(vt + d * 16448 + kv0 + g * 8),
                (LDS_AS void*)(void*)(vbuf + (i * 256 + wave * 64) * 8), 16, 0, 0);
        }
        __syncthreads();

        // QK^T: each B-frag feeds both q-subtiles
        floatx4 sv[2][4];
        #pragma unroll
        for (int u = 0; u < 2; u++)
            #pragma unroll
            for (int nt = 0; nt < 4; nt++) { sv[u][nt][0]=0.f; sv[u][nt][1]=0.f; sv[u][nt][2]=0.f; sv[u][nt][3]=0.f; }
        #pragma unroll
        for (int nt = 0; nt < 4; nt++) {
            const unsigned short* krow = kbuf + (nt * 16 + c) * 256;
            #pragma unroll
            for (int ks = 0; ks < 8; ks++) {
                int p = ((ks >> 1) * 8) | ((((ks & 1) << 2) + quad) ^ cx);
                shortx8 b = *(const shortx8*)(krow + p * 8);
                sv[0][nt] = MFMA_BF16(aQ[0][ks], b, sv[0][nt]);
                sv[1][nt] = MFMA_BF16(aQ[1][ks], b, sv[1][nt]);
            }
        }
        // online softmax (log2 domain)
        float alpha[2][4];
        #pragma unroll
        for (int u = 0; u < 2; u++) {
            #pragma unroll
            for (int r = 0; r < 4; r++) {
                float mx = fmaxf(fmaxf(sv[u][0][r], sv[u][1][r]), fmaxf(sv[u][2][r], sv[u][3][r]));
                #pragma unroll
                for (int off = 1; off < 16; off <<= 1) mx = fmaxf(mx, __shfl_xor(mx, off));
                float mn = fmaxf(m_i[u][r], mx);
                alpha[u][r] = EXP2F(m_i[u][r] - mn);
                m_i[u][r] = mn;
                float rs = 0.f;
                #pragma unroll
                for (int nt = 0; nt < 4; nt++) {
                    float pv = EXP2F(sv[u][nt][r] - mn);
                    sv[u][nt][r] = pv;
                    rs += pv;
                }
                #pragma unroll
                for (int off = 1; off < 16; off <<= 1) rs += __shfl_xor(rs, off);
                l_i[u][r] = l_i[u][r] * alpha[u][r] + rs;
            }
        }
        // P -> LDS (wave-private, XOR-swizzled granules: conflict-free write & read)
        #pragma unroll
        for (int u = 0; u < 2; u++)
            #pragma unroll
            for (int nt = 0; nt < 4; nt++)
                #pragma unroll
                for (int r = 0; r < 4; r++) {
                    int rho = u * 16 + quad * 4 + r;
                    pw[rho * 64 + (((nt * 2 + (c >> 3)) ^ (rho & 7)) * 8) + (c & 7)] = f2b(sv[u][nt][r]);
                }
        shortx8 aP[2][2];
        #pragma unroll
        for (int u = 0; u < 2; u++)
            #pragma unroll
            for (int h = 0; h < 2; h++)
                aP[u][h] = *(const shortx8*)(pw + (u * 16 + c) * 64 + (((h * 4 + quad) ^ cx) * 8));
        // rescale O
        #pragma unroll
        for (int u = 0; u < 2; u++)
            #pragma unroll
            for (int nt = 0; nt < 16; nt++) {
                o[u][nt][0] *= alpha[u][0]; o[u][nt][1] *= alpha[u][1];
                o[u][nt][2] *= alpha[u][2]; o[u][nt][3] *= alpha[u][3];
            }
        // PV: each V B-frag feeds both subtiles
        const int p0 = quad ^ cx;
        const int p1 = (quad + 4) ^ cx;
        #pragma unroll
        for (int nt = 0; nt < 16; nt++) {
            const unsigned short* vrow = vbuf + (nt * 16 + c) * 64;
            shortx8 b0 = *(const shortx8*)(vrow + p0 * 8);
            o[0][nt] = MFMA_BF16(aP[0][0], b0, o[0][nt]);
            o[1][nt] = MFMA_BF16(aP[1][0], b0, o[1][nt]);
            shortx8 b1 = *(const shortx8*)(vrow + p1 * 8);
            o[0][nt] = MFMA_BF16(aP[0][1], b1, o[0][nt]);
            o[1][nt] = MFMA_BF16(aP[1][1], b1, o[1][nt]);
        }
        __syncthreads();
    }
    half_t* Ob = Opart + (size_t)s * (4096 * 256);
    #pragma unroll
    for (int u = 0; u < 2; u++)
        #pragma unroll
        for (int nt = 0; nt < 16; nt++)
            #pragma unroll
            for (int r = 0; r < 4; r++)
                Ob[(qrow0 + u * 16 + quad * 4 + r) * 256 + nt * 16 + c] = (half_t)o[u][nt][r];
    if (c == 0) {
        #pragma unroll
        for (int u = 0; u < 2; u++)
            #pragma unroll
            for (int r = 0; r < 4; r++) {
                Mpart[s * 4096 + qrow0 + u * 16 + quad * 4 + r] = m_i[u][r];
                Lpart[s * 4096 + qrow0 + u * 16 + quad * 4 + r] = l_i[u][r];
            }
    }
}

// ---------------- split combine -> x (bf16) ----------------
__global__ __launch_bounds__(256) void combine_kernel(
    const half_t* __restrict__ Opart, const float* __restrict__ Mpart,
    const float* __restrict__ Lpart, unsigned short* __restrict__ xb)
{
    int idx = blockIdx.x * 256 + threadIdx.x;   // 131072 threads x 8 elems
    int row = idx >> 5;
    int d0 = (idx & 31) * 8;
    float mx = NEG_INF;
    float ms[NSPLIT];
    #pragma unroll
    for (int sp = 0; sp < NSPLIT; sp++) { ms[sp] = Mpart[sp * 4096 + row]; mx = fmaxf(mx, ms[sp]); }
    float den = 0.f, w[NSPLIT];
    #pragma unroll
    for (int sp = 0; sp < NSPLIT; sp++) {
        w[sp] = EXP2F(ms[sp] - mx);
        den += w[sp] * Lpart[sp * 4096 + row];
    }
    float inv = 1.0f / den;
    float acc[8];
    #pragma unroll
    for (int j = 0; j < 8; j++) acc[j] = 0.f;
    #pragma unroll
    for (int sp = 0; sp < NSPLIT; sp++) {
        const half_t* op = Opart + (size_t)sp * (4096 * 256) + row * 256 + d0;
        float wn = w[sp] * inv;
        #pragma unroll
        for (int j = 0; j < 8; j++) acc[j] += wn * (float)op[j];
    }
    shortx8 xv;
    #pragma unroll
    for (int j = 0; j < 8; j++) xv[j] = (short)f2b(acc[j]);
    *(shortx8*)(xb + row * 256 + d0) = xv;
}

// ---------------- output projection (64 rows x 64 cols per block) ----------------
__global__ __launch_bounds__(256) void oproj_kernel(
    const unsigned short* __restrict__ xb, const unsigned short* __restrict__ wot,
    const float* __restrict__ bo, float* __restrict__ outp)
{
    const int tid = threadIdx.x;
    const int wave = tid >> 6, lane = tid & 63;
    const int c = lane & 15, quad = lane >> 4;
    const int m0 = blockIdx.x * 64;
    const int n0 = blockIdx.y * 64;

    shortx8 aX[8];
    #pragma unroll
    for (int ks = 0; ks < 8; ks++)
        aX[ks] = *(const shortx8*)(xb + (m0 + wave * 16 + c) * 256 + ks * 32 + quad * 8);
    floatx4 acc[4];
    #pragma unroll
    for (int nt = 0; nt < 4; nt++) { acc[nt][0]=0.f; acc[nt][1]=0.f; acc[nt][2]=0.f; acc[nt][3]=0.f; }
    #pragma unroll
    for (int nt = 0; nt < 4; nt++) {
        #pragma unroll
        for (int ks = 0; ks < 8; ks++) {
            shortx8 b = *(const shortx8*)(wot + (n0 + nt * 16 + c) * 256 + ks * 32 + quad * 8);
            acc[nt] = MFMA_BF16(aX[ks], b, acc[nt]);
        }
    }
    #pragma unroll
    for (int nt = 0; nt < 4; nt++) {
        const int col = n0 + nt * 16 + c;
        #pragma unroll
        for (int r = 0; r < 4; r++) {
            const int row = m0 + wave * 16 + quad * 4 + r;
            outp[row * 256 + col] = acc[nt][r] + bo[col];
        }
    }
}

extern "C" void kernel_launch(void* const* d_in, const int* in_sizes, int n_in,
                              void* d_out, int out_size, void* d_ws, size_t ws_size,
                              hipStream_t stream) {
    const float* query = (const float*)d_in[0];
    const float* key   = (const float*)d_in[1];
    const float* value = (const float*)d_in[2];
    const float* cosb  = (const float*)d_in[3];
    const float* sinb  = (const float*)d_in[4];
    const float* wq    = (const float*)d_in[5];
    const float* bq    = (const float*)d_in[6];
    const float* wk    = (const float*)d_in[7];
    const float* bk    = (const float*)d_in[8];
    const float* wv    = (const float*)d_in[9];
    const float* bv    = (const float*)d_in[10];
    const float* wo    = (const float*)d_in[11];
    const float* bo    = (const float*)d_in[12];
    const int*   nk    = (const int*)d_in[13];

    char* ws = (char*)d_ws;
    unsigned short* wqt = (unsigned short*)(ws + 0);          // 128 KB
    unsigned short* wkt = (unsigned short*)(ws + 131072);     // 32 KB
    unsigned short* wvt = (unsigned short*)(ws + 163840);     // 32 KB
    unsigned short* wot = (unsigned short*)(ws + 196608);     // 128 KB
    unsigned short* qr  = (unsigned short*)(ws + 327680);     // 2 MB (dead after flash)
    unsigned short* xb  = (unsigned short*)(ws + 327680);     // aliases qr
    unsigned short* krw = (unsigned short*)(ws + 2424832);    // 8.42 MB
    unsigned short* vtg = (unsigned short*)(ws + 10846208);   // 8.42 MB
    half_t* Opart = (half_t*)(ws + 19267584);                 // 32 MB (16 splits, fp16)
    float* Mpart = (float*)(ws + 52822016);                   // 256 KB
    float* Lpart = (float*)(ws + 53084160);                   // 256 KB
    float* outp  = (float*)d_out;

    wtrans_kernel<<<dim3(640), dim3(256), 0, stream>>>(wq, wk, wv, wo, wqt, wkt, wvt, wot);
    qproj_kernel<<<dim3(64, 4), dim3(256), 0, stream>>>(query, wqt, bq, cosb, sinb, qr);
    kvproj_kernel<<<dim3(257, 2), dim3(256), 0, stream>>>(key, value, wkt, wvt, bk, bv, cosb, sinb, nk, krw, vtg);
    flash_kernel<<<dim3(32, NSPLIT), dim3(256), 0, stream>>>(qr, krw, vtg, Opart, Mpart, Lpart);
    combine_kernel<<<dim3(512), dim3(256), 0, stream>>>(Opart, Mpart, Lpart, xb);
    oproj_kernel<<<dim3(64, 4), dim3(256), 0, stream>>>(xb, wot, bo, outp);
}

// Round 3
// 422.069 us; speedup vs baseline: 1.0831x; 1.0831x over previous
//
#include <hip/hip_runtime.h>
#include <hip/hip_bf16.h>

typedef __attribute__((ext_vector_type(4))) float floatx4;
typedef __attribute__((ext_vector_type(8))) short shortx8;
typedef __attribute__((ext_vector_type(4))) short shortx4;
typedef _Float16 half_t;

#define MFMA_BF16(A,B,C) __builtin_amdgcn_mfma_f32_16x16x32_bf16((A),(B),(C),0,0,0)
#define NEG_INF (-__builtin_inff())

static __device__ __forceinline__ unsigned short f2b(float f) {
    union { float f; unsigned u; } v; v.f = f;
    unsigned r = v.u + 0x7FFFu + ((v.u >> 16) & 1u);   // RNE fp32 -> bf16
    return (unsigned short)(r >> 16);
}
static __device__ __forceinline__ unsigned pack_bf16(float lo, float hi) {
    return (unsigned)f2b(lo) | ((unsigned)f2b(hi) << 16);
}
static __device__ __forceinline__ unsigned pack_half(float lo, float hi) {
    union { half_t h[2]; unsigned u; } p;
    p.h[0] = (half_t)lo; p.h[1] = (half_t)hi;
    return p.u;
}
static __device__ __forceinline__ float EXP2F(float x) { return __builtin_amdgcn_exp2f(x); }

#define NSPLIT 16
#define NTILES 257

// ---------------- weights: transpose + bf16 ----------------
__global__ __launch_bounds__(256) void wtrans_kernel(
    const float* __restrict__ wq, const float* __restrict__ wk,
    const float* __restrict__ wv, const float* __restrict__ wo,
    unsigned short* __restrict__ wqt, unsigned short* __restrict__ wkt,
    unsigned short* __restrict__ wvt, unsigned short* __restrict__ wot)
{
    int gid = blockIdx.x * 256 + threadIdx.x;
    if (gid < 65536) {
        int n = gid >> 8, k = gid & 255;
        wqt[gid] = f2b(wq[k * 256 + n]);
    } else if (gid < 81920) {
        int j = gid - 65536, n = j >> 6, k = j & 63;
        wkt[j] = f2b(wk[k * 256 + n]);
    } else if (gid < 98304) {
        int j = gid - 81920, n = j >> 6, k = j & 63;
        wvt[j] = f2b(wv[k * 256 + n]);
    } else {
        int j = gid - 98304, n = j >> 8, k = j & 255;
        wot[j] = f2b(wo[k * 256 + n]);
    }
}

// ---------------- q projection + RoPE + scale (64 rows x 64 cols per block) ----------------
__global__ __launch_bounds__(256) void qproj_kernel(
    const float* __restrict__ query, const unsigned short* __restrict__ wqt,
    const float* __restrict__ bq, const float* __restrict__ cosb,
    const float* __restrict__ sinb, unsigned short* __restrict__ qr)
{
    const int tid = threadIdx.x;
    const int wave = tid >> 6, lane = tid & 63;
    const int c = lane & 15, quad = lane >> 4;
    const int m0 = blockIdx.x * 64;
    const int n0 = blockIdx.y * 64;

    shortx8 aA[8];
    {
        const int mrow = m0 + wave * 16 + c;
        #pragma unroll
        for (int ks = 0; ks < 8; ks++) {
            const float* p = query + mrow * 256 + ks * 32 + quad * 8;
            floatx4 f0 = *(const floatx4*)p;
            floatx4 f1 = *(const floatx4*)(p + 4);
            shortx8 a;
            #pragma unroll
            for (int j = 0; j < 4; j++) { a[j] = (short)f2b(f0[j]); a[j + 4] = (short)f2b(f1[j]); }
            aA[ks] = a;
        }
    }
    floatx4 acc[4];
    #pragma unroll
    for (int nt = 0; nt < 4; nt++) { acc[nt][0]=0.f; acc[nt][1]=0.f; acc[nt][2]=0.f; acc[nt][3]=0.f; }
    #pragma unroll
    for (int nt = 0; nt < 4; nt++) {
        #pragma unroll
        for (int ks = 0; ks < 8; ks++) {
            shortx8 b = *(const shortx8*)(wqt + (n0 + nt * 16 + c) * 256 + ks * 32 + quad * 8);
            acc[nt] = MFMA_BF16(aA[ks], b, acc[nt]);
        }
    }
    const float sc = 0.09016844005556021f;  // (1/16) * log2(e)
    #pragma unroll
    for (int nt = 0; nt < 4; nt++) {
        const int col = n0 + nt * 16 + c;
        float vals[4];
        #pragma unroll
        for (int r = 0; r < 4; r++) {
            const int row = m0 + wave * 16 + quad * 4 + r;
            float v = acc[nt][r] + bq[col];
            float partner = __shfl_xor(v, 1);
            float cv = cosb[row * 256 + col];
            float sn = sinb[row * 256 + col];
            float rot = (col & 1) ? partner : -partner;
            vals[r] = (v * cv + rot * sn) * sc;
        }
        #pragma unroll
        for (int r2 = 0; r2 < 4; r2 += 2) {
            float a = vals[r2], b = vals[r2 + 1];
            float ax = __shfl_xor(a, 1), bx = __shfl_xor(b, 1);
            float lo = (c & 1) ? bx : a;
            float hi = (c & 1) ? b : ax;
            int row = m0 + wave * 16 + quad * 4 + r2 + (c & 1);
            *(unsigned*)(qr + row * 256 + n0 + nt * 16 + (c & ~1)) = pack_bf16(lo, hi);
        }
    }
}

// ---------------- fused k/v projection ----------------
__global__ __launch_bounds__(256) void kvproj_kernel(
    const float* __restrict__ key, const float* __restrict__ value,
    const unsigned short* __restrict__ wkt, const unsigned short* __restrict__ wvt,
    const float* __restrict__ bk, const float* __restrict__ bv,
    const float* __restrict__ cosb, const float* __restrict__ sinb,
    const int* __restrict__ nkx, unsigned short* __restrict__ krw,
    unsigned short* __restrict__ vtg)
{
    __shared__ unsigned short tbuf[256 * 72];
    const int tid = threadIdx.x;
    const int wave = tid >> 6, lane = tid & 63;
    const int c = lane & 15, quad = lane >> 4;
    const int m0 = blockIdx.x * 64;
    const int isv = blockIdx.y;

    const float* src = isv ? value : key;
    const unsigned short* wt = isv ? wvt : wkt;
    const float* bias = isv ? bv : bk;

    shortx8 aA[2];
    {
        const int mrow = m0 + wave * 16 + c;
        #pragma unroll
        for (int ks = 0; ks < 2; ks++) {
            const float* p = src + mrow * 64 + ks * 32 + quad * 8;
            floatx4 f0 = *(const floatx4*)p;
            floatx4 f1 = *(const floatx4*)(p + 4);
            shortx8 a;
            #pragma unroll
            for (int j = 0; j < 4; j++) { a[j] = (short)f2b(f0[j]); a[j + 4] = (short)f2b(f1[j]); }
            aA[ks] = a;
        }
    }
    floatx4 acc[16];
    #pragma unroll
    for (int nt = 0; nt < 16; nt++) { acc[nt][0]=0.f; acc[nt][1]=0.f; acc[nt][2]=0.f; acc[nt][3]=0.f; }
    #pragma unroll
    for (int nt = 0; nt < 16; nt++) {
        #pragma unroll
        for (int ks = 0; ks < 2; ks++) {
            shortx8 b = *(const shortx8*)(wt + (nt * 16 + c) * 64 + ks * 32 + quad * 8);
            acc[nt] = MFMA_BF16(aA[ks], b, acc[nt]);
        }
    }
    if (!isv) {
        // K path: bias + partial RoPE, row-major bf16 out (pair-packed 4B stores)
        const int n_rot = 16448 - nkx[0];
        int rep = n_rot / 4096; if (rep < 1) rep = 1;
        int rc4[4];
        #pragma unroll
        for (int r = 0; r < 4; r++) {
            int row = m0 + wave * 16 + quad * 4 + r;
            rc4[r] = row / rep;
        }
        #pragma unroll
        for (int nt = 0; nt < 16; nt++) {
            const int col = nt * 16 + c;
            float vals[4];
            #pragma unroll
            for (int r = 0; r < 4; r++) {
                const int row = m0 + wave * 16 + quad * 4 + r;
                float v = acc[nt][r] + bias[col];
                float partner = __shfl_xor(v, 1);
                float outv = v;
                if (row < n_rot) {
                    float cv = cosb[rc4[r] * 256 + col];
                    float sn = sinb[rc4[r] * 256 + col];
                    float rot = (col & 1) ? partner : -partner;
                    outv = v * cv + rot * sn;
                }
                vals[r] = outv;
            }
            #pragma unroll
            for (int r2 = 0; r2 < 4; r2 += 2) {
                float a = vals[r2], b = vals[r2 + 1];
                float ax = __shfl_xor(a, 1), bx = __shfl_xor(b, 1);
                float lo = (c & 1) ? bx : a;
                float hi = (c & 1) ? b : ax;
                int row = m0 + wave * 16 + quad * 4 + r2 + (c & 1);
                *(unsigned*)(krw + row * 256 + nt * 16 + (c & ~1)) = pack_bf16(lo, hi);
            }
        }
    } else {
        // V path: bias, transposed store vt[d][kv] via LDS (16B coalesced)
        #pragma unroll
        for (int nt = 0; nt < 16; nt++) {
            const int col = nt * 16 + c;
            #pragma unroll
            for (int r = 0; r < 4; r++) {
                const int rl = wave * 16 + quad * 4 + r;
                tbuf[col * 72 + rl] = f2b(acc[nt][r] + bias[col]);
            }
        }
        __syncthreads();
        #pragma unroll
        for (int i = 0; i < 8; i++) {
            int G = i * 256 + tid;
            int n = G >> 3, g = G & 7;
            *(floatx4*)(vtg + n * 16448 + m0 + g * 8) = *(const floatx4*)(tbuf + n * 72 + g * 8);
        }
    }
}

// ---------------- flash attention: 8 waves x 32 q-rows, BM=256, 16 splits ----------------
__global__ __launch_bounds__(512, 2) void flash_kernel(
    const unsigned short* __restrict__ qr, const unsigned short* __restrict__ kr,
    const unsigned short* __restrict__ vt, half_t* __restrict__ Opart,
    float* __restrict__ Mpart, float* __restrict__ Lpart)
{
    __shared__ unsigned short smem[49152];   // 96 KB -> exactly 1 block/CU
    unsigned short* kbuf = smem;             // 64 kv x 256 d, swizzled granules
    unsigned short* vbuf = smem + 16384;     // 256 d x 64 kv, swizzled granules
    unsigned short* pbuf = smem + 32768;     // per-wave 32 x 64, swizzled granules

    const int tid = threadIdx.x;
    const int wave = tid >> 6, lane = tid & 63;
    const int c = lane & 15, quad = lane >> 4;
    const int cx = c & 7;
    const int qrow0 = blockIdx.x * 256 + wave * 32;
    const int s = blockIdx.y;
    const int t0 = (s * NTILES) / NSPLIT, t1 = ((s + 1) * NTILES) / NSPLIT;
    unsigned short* pw = pbuf + wave * 2048;

    shortx8 aQ[2][8];
    #pragma unroll
    for (int u = 0; u < 2; u++)
        #pragma unroll
        for (int ks = 0; ks < 8; ks++)
            aQ[u][ks] = *(const shortx8*)(qr + (qrow0 + u * 16 + c) * 256 + ks * 32 + quad * 8);

    floatx4 o[2][16];
    #pragma unroll
    for (int u = 0; u < 2; u++)
        #pragma unroll
        for (int nt = 0; nt < 16; nt++) { o[u][nt][0]=0.f; o[u][nt][1]=0.f; o[u][nt][2]=0.f; o[u][nt][3]=0.f; }
    float m_i[2][4], l_i[2][4];
    #pragma unroll
    for (int u = 0; u < 2; u++)
        #pragma unroll
        for (int r = 0; r < 4; r++) { m_i[u][r] = NEG_INF; l_i[u][r] = 0.f; }

    for (int t = t0; t < t1; t++) {
        const int kv0 = t * 64;
        // stage K tile (32 KB): VGPR-mediated loads (L1/L2-allocating), swizzle in source addr
        floatx4 kst[4], vst[4];
        #pragma unroll
        for (int i = 0; i < 4; i++) {
            int L = i * 512 + tid;
            int kv = L >> 5, p = L & 31;
            int g = (p & 24) | ((p & 7) ^ (kv & 7));
            kst[i] = *(const floatx4*)(kr + (kv0 + kv) * 256 + g * 8);
        }
        #pragma unroll
        for (int i = 0; i < 4; i++) {
            int L = i * 512 + tid;
            int d = L >> 3, p = L & 7;
            int g = p ^ (d & 7);
            vst[i] = *(const floatx4*)(vt + d * 16448 + kv0 + g * 8);
        }
        #pragma unroll
        for (int i = 0; i < 4; i++) *(floatx4*)(kbuf + (i * 512 + tid) * 8) = kst[i];
        #pragma unroll
        for (int i = 0; i < 4; i++) *(floatx4*)(vbuf + (i * 512 + tid) * 8) = vst[i];
        __syncthreads();

        // QK^T: each B-frag feeds both q-subtiles
        floatx4 sv[2][4];
        #pragma unroll
        for (int u = 0; u < 2; u++)
            #pragma unroll
            for (int nt = 0; nt < 4; nt++) { sv[u][nt][0]=0.f; sv[u][nt][1]=0.f; sv[u][nt][2]=0.f; sv[u][nt][3]=0.f; }
        #pragma unroll
        for (int nt = 0; nt < 4; nt++) {
            const unsigned short* krow = kbuf + (nt * 16 + c) * 256;
            #pragma unroll
            for (int ks = 0; ks < 8; ks++) {
                int p = ((ks >> 1) * 8) | ((((ks & 1) << 2) + quad) ^ cx);
                shortx8 b = *(const shortx8*)(krow + p * 8);
                sv[0][nt] = MFMA_BF16(aQ[0][ks], b, sv[0][nt]);
                sv[1][nt] = MFMA_BF16(aQ[1][ks], b, sv[1][nt]);
            }
        }
        // online softmax (log2 domain)
        float alpha[2][4];
        #pragma unroll
        for (int u = 0; u < 2; u++) {
            #pragma unroll
            for (int r = 0; r < 4; r++) {
                float mx = fmaxf(fmaxf(sv[u][0][r], sv[u][1][r]), fmaxf(sv[u][2][r], sv[u][3][r]));
                #pragma unroll
                for (int off = 1; off < 16; off <<= 1) mx = fmaxf(mx, __shfl_xor(mx, off));
                float mn = fmaxf(m_i[u][r], mx);
                alpha[u][r] = EXP2F(m_i[u][r] - mn);
                m_i[u][r] = mn;
                float rs = 0.f;
                #pragma unroll
                for (int nt = 0; nt < 4; nt++) {
                    float pv = EXP2F(sv[u][nt][r] - mn);
                    sv[u][nt][r] = pv;
                    rs += pv;
                }
                #pragma unroll
                for (int off = 1; off < 16; off <<= 1) rs += __shfl_xor(rs, off);
                l_i[u][r] = l_i[u][r] * alpha[u][r] + rs;
            }
        }
        // P -> LDS, pair-packed b32 writes (wave-private, swizzled)
        #pragma unroll
        for (int u = 0; u < 2; u++)
            #pragma unroll
            for (int nt = 0; nt < 4; nt++)
                #pragma unroll
                for (int r2 = 0; r2 < 4; r2 += 2) {
                    float a = sv[u][nt][r2], b = sv[u][nt][r2 + 1];
                    float ax = __shfl_xor(a, 1), bx = __shfl_xor(b, 1);
                    float lo = (c & 1) ? bx : a;
                    float hi = (c & 1) ? b : ax;
                    int rho = u * 16 + quad * 4 + r2 + (c & 1);
                    int g = (nt * 2 + (c >> 3)) ^ (rho & 7);
                    *(unsigned*)(pw + rho * 64 + g * 8 + (c & 6)) = pack_bf16(lo, hi);
                }
        shortx8 aP[2][2];
        #pragma unroll
        for (int u = 0; u < 2; u++)
            #pragma unroll
            for (int h = 0; h < 2; h++)
                aP[u][h] = *(const shortx8*)(pw + (u * 16 + c) * 64 + (((h * 4 + quad) ^ cx) * 8));
        // rescale O
        #pragma unroll
        for (int u = 0; u < 2; u++)
            #pragma unroll
            for (int nt = 0; nt < 16; nt++) {
                o[u][nt][0] *= alpha[u][0]; o[u][nt][1] *= alpha[u][1];
                o[u][nt][2] *= alpha[u][2]; o[u][nt][3] *= alpha[u][3];
            }
        // PV: each V B-frag feeds both subtiles
        const int p0 = quad ^ cx;
        const int p1 = (quad + 4) ^ cx;
        #pragma unroll
        for (int nt = 0; nt < 16; nt++) {
            const unsigned short* vrow = vbuf + (nt * 16 + c) * 64;
            shortx8 b0 = *(const shortx8*)(vrow + p0 * 8);
            o[0][nt] = MFMA_BF16(aP[0][0], b0, o[0][nt]);
            o[1][nt] = MFMA_BF16(aP[1][0], b0, o[1][nt]);
            shortx8 b1 = *(const shortx8*)(vrow + p1 * 8);
            o[0][nt] = MFMA_BF16(aP[0][1], b1, o[0][nt]);
            o[1][nt] = MFMA_BF16(aP[1][1], b1, o[1][nt]);
        }
        __syncthreads();
    }
    // O partial store: fp16 pair-packed 4B stores
    half_t* Ob = Opart + (size_t)s * (4096 * 256);
    #pragma unroll
    for (int u = 0; u < 2; u++)
        #pragma unroll
        for (int nt = 0; nt < 16; nt++)
            #pragma unroll
            for (int r2 = 0; r2 < 4; r2 += 2) {
                float a = o[u][nt][r2], b = o[u][nt][r2 + 1];
                float ax = __shfl_xor(a, 1), bx = __shfl_xor(b, 1);
                float lo = (c & 1) ? bx : a;
                float hi = (c & 1) ? b : ax;
                int row = qrow0 + u * 16 + quad * 4 + r2 + (c & 1);
                *(unsigned*)(Ob + row * 256 + nt * 16 + (c & ~1)) = pack_half(lo, hi);
            }
    if (c == 0) {
        #pragma unroll
        for (int u = 0; u < 2; u++)
            #pragma unroll
            for (int r = 0; r < 4; r++) {
                Mpart[s * 4096 + qrow0 + u * 16 + quad * 4 + r] = m_i[u][r];
                Lpart[s * 4096 + qrow0 + u * 16 + quad * 4 + r] = l_i[u][r];
            }
    }
}

// ---------------- split combine -> x (bf16) ----------------
__global__ __launch_bounds__(256) void combine_kernel(
    const half_t* __restrict__ Opart, const float* __restrict__ Mpart,
    const float* __restrict__ Lpart, unsigned short* __restrict__ xb)
{
    int idx = blockIdx.x * 256 + threadIdx.x;   // 131072 threads x 8 elems
    int row = idx >> 5;
    int d0 = (idx & 31) * 8;
    float mx = NEG_INF;
    float ms[NSPLIT];
    #pragma unroll
    for (int sp = 0; sp < NSPLIT; sp++) { ms[sp] = Mpart[sp * 4096 + row]; mx = fmaxf(mx, ms[sp]); }
    float den = 0.f, w[NSPLIT];
    #pragma unroll
    for (int sp = 0; sp < NSPLIT; sp++) {
        w[sp] = EXP2F(ms[sp] - mx);
        den += w[sp] * Lpart[sp * 4096 + row];
    }
    float inv = 1.0f / den;
    float acc[8];
    #pragma unroll
    for (int j = 0; j < 8; j++) acc[j] = 0.f;
    #pragma unroll
    for (int sp = 0; sp < NSPLIT; sp++) {
        const half_t* op = Opart + (size_t)sp * (4096 * 256) + row * 256 + d0;
        float wn = w[sp] * inv;
        #pragma unroll
        for (int j = 0; j < 8; j++) acc[j] += wn * (float)op[j];
    }
    shortx8 xv;
    #pragma unroll
    for (int j = 0; j < 8; j++) xv[j] = (short)f2b(acc[j]);
    *(shortx8*)(xb + row * 256 + d0) = xv;
}

// ---------------- output projection (64 rows x 64 cols per block) ----------------
__global__ __launch_bounds__(256) void oproj_kernel(
    const unsigned short* __restrict__ xb, const unsigned short* __restrict__ wot,
    const float* __restrict__ bo, float* __restrict__ outp)
{
    const int tid = threadIdx.x;
    const int wave = tid >> 6, lane = tid & 63;
    const int c = lane & 15, quad = lane >> 4;
    const int m0 = blockIdx.x * 64;
    const int n0 = blockIdx.y * 64;

    shortx8 aX[8];
    #pragma unroll
    for (int ks = 0; ks < 8; ks++)
        aX[ks] = *(const shortx8*)(xb + (m0 + wave * 16 + c) * 256 + ks * 32 + quad * 8);
    floatx4 acc[4];
    #pragma unroll
    for (int nt = 0; nt < 4; nt++) { acc[nt][0]=0.f; acc[nt][1]=0.f; acc[nt][2]=0.f; acc[nt][3]=0.f; }
    #pragma unroll
    for (int nt = 0; nt < 4; nt++) {
        #pragma unroll
        for (int ks = 0; ks < 8; ks++) {
            shortx8 b = *(const shortx8*)(wot + (n0 + nt * 16 + c) * 256 + ks * 32 + quad * 8);
            acc[nt] = MFMA_BF16(aX[ks], b, acc[nt]);
        }
    }
    #pragma unroll
    for (int nt = 0; nt < 4; nt++) {
        const int col = n0 + nt * 16 + c;
        #pragma unroll
        for (int r = 0; r < 4; r++) {
            const int row = m0 + wave * 16 + quad * 4 + r;
            outp[row * 256 + col] = acc[nt][r] + bo[col];
        }
    }
}

extern "C" void kernel_launch(void* const* d_in, const int* in_sizes, int n_in,
                              void* d_out, int out_size, void* d_ws, size_t ws_size,
                              hipStream_t stream) {
    const float* query = (const float*)d_in[0];
    const float* key   = (const float*)d_in[1];
    const float* value = (const float*)d_in[2];
    const float* cosb  = (const float*)d_in[3];
    const float* sinb  = (const float*)d_in[4];
    const float* wq    = (const float*)d_in[5];
    const float* bq    = (const float*)d_in[6];
    const float* wk    = (const float*)d_in[7];
    const float* bk    = (const float*)d_in[8];
    const float* wv    = (const float*)d_in[9];
    const float* bv    = (const float*)d_in[10];
    const float* wo    = (const float*)d_in[11];
    const float* bo    = (const float*)d_in[12];
    const int*   nk    = (const int*)d_in[13];

    char* ws = (char*)d_ws;
    unsigned short* wqt = (unsigned short*)(ws + 0);          // 128 KB
    unsigned short* wkt = (unsigned short*)(ws + 131072);     // 32 KB
    unsigned short* wvt = (unsigned short*)(ws + 163840);     // 32 KB
    unsigned short* wot = (unsigned short*)(ws + 196608);     // 128 KB
    unsigned short* qr  = (unsigned short*)(ws + 327680);     // 2 MB (dead after flash)
    unsigned short* xb  = (unsigned short*)(ws + 327680);     // aliases qr
    unsigned short* krw = (unsigned short*)(ws + 2424832);    // 8.42 MB
    unsigned short* vtg = (unsigned short*)(ws + 10846208);   // 8.42 MB
    half_t* Opart = (half_t*)(ws + 19267584);                 // 32 MB (16 splits, fp16)
    float* Mpart = (float*)(ws + 52822016);                   // 256 KB
    float* Lpart = (float*)(ws + 53084160);                   // 256 KB
    float* outp  = (float*)d_out;

    wtrans_kernel<<<dim3(640), dim3(256), 0, stream>>>(wq, wk, wv, wo, wqt, wkt, wvt, wot);
    qproj_kernel<<<dim3(64, 4), dim3(256), 0, stream>>>(query, wqt, bq, cosb, sinb, qr);
    kvproj_kernel<<<dim3(257, 2), dim3(256), 0, stream>>>(key, value, wkt, wvt, bk, bv, cosb, sinb, nk, krw, vtg);
    flash_kernel<<<dim3(16, NSPLIT), dim3(512), 0, stream>>>(qr, krw, vtg, Opart, Mpart, Lpart);
    combine_kernel<<<dim3(512), dim3(256), 0, stream>>>(Opart, Mpart, Lpart, xb);
    oproj_kernel<<<dim3(64, 4), dim3(256), 0, stream>>>(xb, wot, bo, outp);
}

// Round 4
// 260.102 us; speedup vs baseline: 1.7575x; 1.6227x over previous
//
#include <hip/hip_runtime.h>
#include <hip/hip_bf16.h>

typedef __attribute__((ext_vector_type(4))) float floatx4;
typedef __attribute__((ext_vector_type(8))) short shortx8;
typedef __attribute__((ext_vector_type(4))) short shortx4;
typedef _Float16 half_t;

#define MFMA_BF16(A,B,C) __builtin_amdgcn_mfma_f32_16x16x32_bf16((A),(B),(C),0,0,0)
#define NEG_INF (-__builtin_inff())

static __device__ __forceinline__ unsigned short f2b(float f) {
    union { float f; unsigned u; } v; v.f = f;
    unsigned r = v.u + 0x7FFFu + ((v.u >> 16) & 1u);   // RNE fp32 -> bf16
    return (unsigned short)(r >> 16);
}
static __device__ __forceinline__ unsigned pack_bf16(float lo, float hi) {
    return (unsigned)f2b(lo) | ((unsigned)f2b(hi) << 16);
}
static __device__ __forceinline__ unsigned pack_half(float lo, float hi) {
    union { half_t h[2]; unsigned u; } p;
    p.h[0] = (half_t)lo; p.h[1] = (half_t)hi;
    return p.u;
}
static __device__ __forceinline__ float EXP2F(float x) { return __builtin_amdgcn_exp2f(x); }

#define NSPLIT 8
#define NTILES 257

// ---------------- weights: transpose + bf16 ----------------
__global__ __launch_bounds__(256) void wtrans_kernel(
    const float* __restrict__ wq, const float* __restrict__ wk,
    const float* __restrict__ wv, const float* __restrict__ wo,
    unsigned short* __restrict__ wqt, unsigned short* __restrict__ wkt,
    unsigned short* __restrict__ wvt, unsigned short* __restrict__ wot)
{
    int gid = blockIdx.x * 256 + threadIdx.x;
    if (gid < 65536) {
        int n = gid >> 8, k = gid & 255;
        wqt[gid] = f2b(wq[k * 256 + n]);
    } else if (gid < 81920) {
        int j = gid - 65536, n = j >> 6, k = j & 63;
        wkt[j] = f2b(wk[k * 256 + n]);
    } else if (gid < 98304) {
        int j = gid - 81920, n = j >> 6, k = j & 63;
        wvt[j] = f2b(wv[k * 256 + n]);
    } else {
        int j = gid - 98304, n = j >> 8, k = j & 255;
        wot[j] = f2b(wo[k * 256 + n]);
    }
}

// ---------------- q projection + RoPE + scale (64 rows x 64 cols per block) ----------------
__global__ __launch_bounds__(256) void qproj_kernel(
    const float* __restrict__ query, const unsigned short* __restrict__ wqt,
    const float* __restrict__ bq, const float* __restrict__ cosb,
    const float* __restrict__ sinb, unsigned short* __restrict__ qr)
{
    const int tid = threadIdx.x;
    const int wave = tid >> 6, lane = tid & 63;
    const int c = lane & 15, quad = lane >> 4;
    const int m0 = blockIdx.x * 64;
    const int n0 = blockIdx.y * 64;

    shortx8 aA[8];
    {
        const int mrow = m0 + wave * 16 + c;
        #pragma unroll
        for (int ks = 0; ks < 8; ks++) {
            const float* p = query + mrow * 256 + ks * 32 + quad * 8;
            floatx4 f0 = *(const floatx4*)p;
            floatx4 f1 = *(const floatx4*)(p + 4);
            shortx8 a;
            #pragma unroll
            for (int j = 0; j < 4; j++) { a[j] = (short)f2b(f0[j]); a[j + 4] = (short)f2b(f1[j]); }
            aA[ks] = a;
        }
    }
    floatx4 acc[4];
    #pragma unroll
    for (int nt = 0; nt < 4; nt++) { acc[nt][0]=0.f; acc[nt][1]=0.f; acc[nt][2]=0.f; acc[nt][3]=0.f; }
    #pragma unroll
    for (int nt = 0; nt < 4; nt++) {
        #pragma unroll
        for (int ks = 0; ks < 8; ks++) {
            shortx8 b = *(const shortx8*)(wqt + (n0 + nt * 16 + c) * 256 + ks * 32 + quad * 8);
            acc[nt] = MFMA_BF16(aA[ks], b, acc[nt]);
        }
    }
    const float sc = 0.09016844005556021f;  // (1/16) * log2(e)
    #pragma unroll
    for (int nt = 0; nt < 4; nt++) {
        const int col = n0 + nt * 16 + c;
        float vals[4];
        #pragma unroll
        for (int r = 0; r < 4; r++) {
            const int row = m0 + wave * 16 + quad * 4 + r;
            float v = acc[nt][r] + bq[col];
            float partner = __shfl_xor(v, 1);
            float cv = cosb[row * 256 + col];
            float sn = sinb[row * 256 + col];
            float rot = (col & 1) ? partner : -partner;
            vals[r] = (v * cv + rot * sn) * sc;
        }
        #pragma unroll
        for (int r2 = 0; r2 < 4; r2 += 2) {
            float a = vals[r2], b = vals[r2 + 1];
            float ax = __shfl_xor(a, 1), bx = __shfl_xor(b, 1);
            float lo = (c & 1) ? bx : a;
            float hi = (c & 1) ? b : ax;
            int row = m0 + wave * 16 + quad * 4 + r2 + (c & 1);
            *(unsigned*)(qr + row * 256 + n0 + nt * 16 + (c & ~1)) = pack_bf16(lo, hi);
        }
    }
}

// ---------------- fused k/v projection ----------------
__global__ __launch_bounds__(256) void kvproj_kernel(
    const float* __restrict__ key, const float* __restrict__ value,
    const unsigned short* __restrict__ wkt, const unsigned short* __restrict__ wvt,
    const float* __restrict__ bk, const float* __restrict__ bv,
    const float* __restrict__ cosb, const float* __restrict__ sinb,
    const int* __restrict__ nkx, unsigned short* __restrict__ krw,
    unsigned short* __restrict__ vtg)
{
    __shared__ unsigned short tbuf[256 * 72];
    const int tid = threadIdx.x;
    const int wave = tid >> 6, lane = tid & 63;
    const int c = lane & 15, quad = lane >> 4;
    const int m0 = blockIdx.x * 64;
    const int isv = blockIdx.y;

    const float* src = isv ? value : key;
    const unsigned short* wt = isv ? wvt : wkt;
    const float* bias = isv ? bv : bk;

    shortx8 aA[2];
    {
        const int mrow = m0 + wave * 16 + c;
        #pragma unroll
        for (int ks = 0; ks < 2; ks++) {
            const float* p = src + mrow * 64 + ks * 32 + quad * 8;
            floatx4 f0 = *(const floatx4*)p;
            floatx4 f1 = *(const floatx4*)(p + 4);
            shortx8 a;
            #pragma unroll
            for (int j = 0; j < 4; j++) { a[j] = (short)f2b(f0[j]); a[j + 4] = (short)f2b(f1[j]); }
            aA[ks] = a;
        }
    }
    floatx4 acc[16];
    #pragma unroll
    for (int nt = 0; nt < 16; nt++) { acc[nt][0]=0.f; acc[nt][1]=0.f; acc[nt][2]=0.f; acc[nt][3]=0.f; }
    #pragma unroll
    for (int nt = 0; nt < 16; nt++) {
        #pragma unroll
        for (int ks = 0; ks < 2; ks++) {
            shortx8 b = *(const shortx8*)(wt + (nt * 16 + c) * 64 + ks * 32 + quad * 8);
            acc[nt] = MFMA_BF16(aA[ks], b, acc[nt]);
        }
    }
    if (!isv) {
        // K path: bias + partial RoPE, row-major bf16 out (pair-packed 4B stores)
        const int n_rot = 16448 - nkx[0];
        int rep = n_rot / 4096; if (rep < 1) rep = 1;
        int rc4[4];
        #pragma unroll
        for (int r = 0; r < 4; r++) {
            int row = m0 + wave * 16 + quad * 4 + r;
            rc4[r] = row / rep;
        }
        #pragma unroll
        for (int nt = 0; nt < 16; nt++) {
            const int col = nt * 16 + c;
            float vals[4];
            #pragma unroll
            for (int r = 0; r < 4; r++) {
                const int row = m0 + wave * 16 + quad * 4 + r;
                float v = acc[nt][r] + bias[col];
                float partner = __shfl_xor(v, 1);
                float outv = v;
                if (row < n_rot) {
                    float cv = cosb[rc4[r] * 256 + col];
                    float sn = sinb[rc4[r] * 256 + col];
                    float rot = (col & 1) ? partner : -partner;
                    outv = v * cv + rot * sn;
                }
                vals[r] = outv;
            }
            #pragma unroll
            for (int r2 = 0; r2 < 4; r2 += 2) {
                float a = vals[r2], b = vals[r2 + 1];
                float ax = __shfl_xor(a, 1), bx = __shfl_xor(b, 1);
                float lo = (c & 1) ? bx : a;
                float hi = (c & 1) ? b : ax;
                int row = m0 + wave * 16 + quad * 4 + r2 + (c & 1);
                *(unsigned*)(krw + row * 256 + nt * 16 + (c & ~1)) = pack_bf16(lo, hi);
            }
        }
    } else {
        // V path: bias, transposed store vt[d][kv] via LDS (16B coalesced)
        #pragma unroll
        for (int nt = 0; nt < 16; nt++) {
            const int col = nt * 16 + c;
            #pragma unroll
            for (int r = 0; r < 4; r++) {
                const int rl = wave * 16 + quad * 4 + r;
                tbuf[col * 72 + rl] = f2b(acc[nt][r] + bias[col]);
            }
        }
        __syncthreads();
        #pragma unroll
        for (int i = 0; i < 8; i++) {
            int G = i * 256 + tid;
            int n = G >> 3, g = G & 7;
            *(floatx4*)(vtg + n * 16448 + m0 + g * 8) = *(const floatx4*)(tbuf + n * 72 + g * 8);
        }
    }
}

// ---------------- flash attention: r1 geometry (BM=128, 8 splits) + reg prefetch ----------------
__global__ __launch_bounds__(512, 2) void flash_kernel(
    const unsigned short* __restrict__ qr, const unsigned short* __restrict__ kr,
    const unsigned short* __restrict__ vt, half_t* __restrict__ Opart,
    float* __restrict__ Mpart, float* __restrict__ Lpart)
{
    __shared__ unsigned short smem[32768];   // 64 KB
    unsigned short* kbuf = smem;             // 64 kv x 256 d, swizzled granules
    unsigned short* vbuf = smem + 16384;     // 256 d x 64 kv, swizzled granules
    unsigned short* pbuf = smem;             // aliases kbuf (guarded by barrier B)

    const int tid = threadIdx.x;
    const int wave = tid >> 6, lane = tid & 63;
    const int c = lane & 15, quad = lane >> 4;
    const int cx = c & 7;
    const int qrow0 = blockIdx.x * 128 + wave * 16;
    const int s = blockIdx.y;
    const int t0 = (s * NTILES) / NSPLIT, t1 = ((s + 1) * NTILES) / NSPLIT;
    unsigned short* pw = pbuf + wave * 1152;   // 16 rows x stride 72

    shortx8 aQ[8];
    #pragma unroll
    for (int ks = 0; ks < 8; ks++)
        aQ[ks] = *(const shortx8*)(qr + (qrow0 + c) * 256 + ks * 32 + quad * 8);

    floatx4 o[16];
    #pragma unroll
    for (int nt = 0; nt < 16; nt++) { o[nt][0]=0.f; o[nt][1]=0.f; o[nt][2]=0.f; o[nt][3]=0.f; }
    float m_i[4] = { NEG_INF, NEG_INF, NEG_INF, NEG_INF };
    float l_i[4] = { 0.f, 0.f, 0.f, 0.f };

    // register prefetch of tile t0
    floatx4 kst[4], vst[4];
    {
        const int kv0 = t0 * 64;
        #pragma unroll
        for (int i = 0; i < 4; i++) {
            int L = i * 512 + tid;
            int kv = L >> 5, p = L & 31;
            int g = (p & 24) | ((p & 7) ^ (kv & 7));
            kst[i] = *(const floatx4*)(kr + (kv0 + kv) * 256 + g * 8);
        }
        #pragma unroll
        for (int i = 0; i < 4; i++) {
            int L = i * 512 + tid;
            int d = L >> 3, p = L & 7;
            int g = p ^ (d & 7);
            vst[i] = *(const floatx4*)(vt + d * 16448 + kv0 + g * 8);
        }
    }

    for (int t = t0; t < t1; t++) {
        // commit prefetched tile to LDS
        #pragma unroll
        for (int i = 0; i < 4; i++) *(floatx4*)(kbuf + (i * 512 + tid) * 8) = kst[i];
        #pragma unroll
        for (int i = 0; i < 4; i++) *(floatx4*)(vbuf + (i * 512 + tid) * 8) = vst[i];
        __syncthreads();                                    // bar A: staging visible

        // issue next tile's global loads NOW — they land during compute
        if (t + 1 < t1) {
            const int kv0n = (t + 1) * 64;
            #pragma unroll
            for (int i = 0; i < 4; i++) {
                int L = i * 512 + tid;
                int kv = L >> 5, p = L & 31;
                int g = (p & 24) | ((p & 7) ^ (kv & 7));
                kst[i] = *(const floatx4*)(kr + (kv0n + kv) * 256 + g * 8);
            }
            #pragma unroll
            for (int i = 0; i < 4; i++) {
                int L = i * 512 + tid;
                int d = L >> 3, p = L & 7;
                int g = p ^ (d & 7);
                vst[i] = *(const floatx4*)(vt + d * 16448 + kv0n + g * 8);
            }
        }

        // QK^T
        floatx4 sv[4];
        #pragma unroll
        for (int nt = 0; nt < 4; nt++) { sv[nt][0]=0.f; sv[nt][1]=0.f; sv[nt][2]=0.f; sv[nt][3]=0.f; }
        #pragma unroll
        for (int nt = 0; nt < 4; nt++) {
            const unsigned short* krow = kbuf + (nt * 16 + c) * 256;
            #pragma unroll
            for (int ks = 0; ks < 8; ks++) {
                int p = ((ks >> 1) * 8) | ((((ks & 1) << 2) + quad) ^ cx);
                shortx8 b = *(const shortx8*)(krow + p * 8);
                sv[nt] = MFMA_BF16(aQ[ks], b, sv[nt]);
            }
        }
        // online softmax (log2 domain)
        float alpha[4];
        #pragma unroll
        for (int r = 0; r < 4; r++) {
            float mx = fmaxf(fmaxf(sv[0][r], sv[1][r]), fmaxf(sv[2][r], sv[3][r]));
            #pragma unroll
            for (int off = 1; off < 16; off <<= 1) mx = fmaxf(mx, __shfl_xor(mx, off));
            float mn = fmaxf(m_i[r], mx);
            alpha[r] = EXP2F(m_i[r] - mn);
            m_i[r] = mn;
            float rs = 0.f;
            #pragma unroll
            for (int nt = 0; nt < 4; nt++) {
                float pv = EXP2F(sv[nt][r] - mn);
                sv[nt][r] = pv;
                rs += pv;
            }
            #pragma unroll
            for (int off = 1; off < 16; off <<= 1) rs += __shfl_xor(rs, off);
            l_i[r] = l_i[r] * alpha[r] + rs;
        }
        __syncthreads();                                    // bar B: kbuf reads done
        // P -> LDS over kbuf alias: pair-packed b32, stride 72 (2-way = free)
        #pragma unroll
        for (int nt = 0; nt < 4; nt++) {
            #pragma unroll
            for (int r2 = 0; r2 < 4; r2 += 2) {
                float a = sv[nt][r2], b = sv[nt][r2 + 1];
                float ax = __shfl_xor(a, 1), bx = __shfl_xor(b, 1);
                float lo = (c & 1) ? bx : a;
                float hi = (c & 1) ? b : ax;
                int rho = quad * 4 + r2 + (c & 1);
                *(unsigned*)(pw + rho * 72 + nt * 16 + (c & ~1)) = pack_bf16(lo, hi);
            }
        }
        shortx8 aP0 = *(const shortx8*)(pw + c * 72 + quad * 8);
        shortx8 aP1 = *(const shortx8*)(pw + c * 72 + 32 + quad * 8);
        // rescale O
        #pragma unroll
        for (int nt = 0; nt < 16; nt++) {
            o[nt][0] *= alpha[0]; o[nt][1] *= alpha[1];
            o[nt][2] *= alpha[2]; o[nt][3] *= alpha[3];
        }
        // PV
        const int p0 = quad ^ cx;
        const int p1 = (quad + 4) ^ cx;
        #pragma unroll
        for (int nt = 0; nt < 16; nt++) {
            const unsigned short* vrow = vbuf + (nt * 16 + c) * 64;
            shortx8 b0 = *(const shortx8*)(vrow + p0 * 8);
            o[nt] = MFMA_BF16(aP0, b0, o[nt]);
            shortx8 b1 = *(const shortx8*)(vrow + p1 * 8);
            o[nt] = MFMA_BF16(aP1, b1, o[nt]);
        }
        __syncthreads();                                    // bar C: reads done before next staging
    }
    // O partial store: fp16 pair-packed 4B stores
    half_t* Ob = Opart + (size_t)s * (4096 * 256);
    #pragma unroll
    for (int nt = 0; nt < 16; nt++) {
        #pragma unroll
        for (int r2 = 0; r2 < 4; r2 += 2) {
            float a = o[nt][r2], b = o[nt][r2 + 1];
            float ax = __shfl_xor(a, 1), bx = __shfl_xor(b, 1);
            float lo = (c & 1) ? bx : a;
            float hi = (c & 1) ? b : ax;
            int row = qrow0 + quad * 4 + r2 + (c & 1);
            *(unsigned*)(Ob + row * 256 + nt * 16 + (c & ~1)) = pack_half(lo, hi);
        }
    }
    if (c == 0) {
        #pragma unroll
        for (int r = 0; r < 4; r++) {
            Mpart[s * 4096 + qrow0 + quad * 4 + r] = m_i[r];
            Lpart[s * 4096 + qrow0 + quad * 4 + r] = l_i[r];
        }
    }
}

// ---------------- split combine -> x (bf16) ----------------
__global__ __launch_bounds__(256) void combine_kernel(
    const half_t* __restrict__ Opart, const float* __restrict__ Mpart,
    const float* __restrict__ Lpart, unsigned short* __restrict__ xb)
{
    int idx = blockIdx.x * 256 + threadIdx.x;   // 131072 threads x 8 elems
    int row = idx >> 5;
    int d0 = (idx & 31) * 8;
    float mx = NEG_INF;
    float ms[NSPLIT];
    #pragma unroll
    for (int sp = 0; sp < NSPLIT; sp++) { ms[sp] = Mpart[sp * 4096 + row]; mx = fmaxf(mx, ms[sp]); }
    float den = 0.f, w[NSPLIT];
    #pragma unroll
    for (int sp = 0; sp < NSPLIT; sp++) {
        w[sp] = EXP2F(ms[sp] - mx);
        den += w[sp] * Lpart[sp * 4096 + row];
    }
    float inv = 1.0f / den;
    float acc[8];
    #pragma unroll
    for (int j = 0; j < 8; j++) acc[j] = 0.f;
    #pragma unroll
    for (int sp = 0; sp < NSPLIT; sp++) {
        const half_t* op = Opart + (size_t)sp * (4096 * 256) + row * 256 + d0;
        float wn = w[sp] * inv;
        #pragma unroll
        for (int j = 0; j < 8; j++) acc[j] += wn * (float)op[j];
    }
    shortx8 xv;
    #pragma unroll
    for (int j = 0; j < 8; j++) xv[j] = (short)f2b(acc[j]);
    *(shortx8*)(xb + row * 256 + d0) = xv;
}

// ---------------- output projection (64 rows x 64 cols per block) ----------------
__global__ __launch_bounds__(256) void oproj_kernel(
    const unsigned short* __restrict__ xb, const unsigned short* __restrict__ wot,
    const float* __restrict__ bo, float* __restrict__ outp)
{
    const int tid = threadIdx.x;
    const int wave = tid >> 6, lane = tid & 63;
    const int c = lane & 15, quad = lane >> 4;
    const int m0 = blockIdx.x * 64;
    const int n0 = blockIdx.y * 64;

    shortx8 aX[8];
    #pragma unroll
    for (int ks = 0; ks < 8; ks++)
        aX[ks] = *(const shortx8*)(xb + (m0 + wave * 16 + c) * 256 + ks * 32 + quad * 8);
    floatx4 acc[4];
    #pragma unroll
    for (int nt = 0; nt < 4; nt++) { acc[nt][0]=0.f; acc[nt][1]=0.f; acc[nt][2]=0.f; acc[nt][3]=0.f; }
    #pragma unroll
    for (int nt = 0; nt < 4; nt++) {
        #pragma unroll
        for (int ks = 0; ks < 8; ks++) {
            shortx8 b = *(const shortx8*)(wot + (n0 + nt * 16 + c) * 256 + ks * 32 + quad * 8);
            acc[nt] = MFMA_BF16(aX[ks], b, acc[nt]);
        }
    }
    #pragma unroll
    for (int nt = 0; nt < 4; nt++) {
        const int col = n0 + nt * 16 + c;
        #pragma unroll
        for (int r = 0; r < 4; r++) {
            const int row = m0 + wave * 16 + quad * 4 + r;
            outp[row * 256 + col] = acc[nt][r] + bo[col];
        }
    }
}

extern "C" void kernel_launch(void* const* d_in, const int* in_sizes, int n_in,
                              void* d_out, int out_size, void* d_ws, size_t ws_size,
                              hipStream_t stream) {
    const float* query = (const float*)d_in[0];
    const float* key   = (const float*)d_in[1];
    const float* value = (const float*)d_in[2];
    const float* cosb  = (const float*)d_in[3];
    const float* sinb  = (const float*)d_in[4];
    const float* wq    = (const float*)d_in[5];
    const float* bq    = (const float*)d_in[6];
    const float* wk    = (const float*)d_in[7];
    const float* bk    = (const float*)d_in[8];
    const float* wv    = (const float*)d_in[9];
    const float* bv    = (const float*)d_in[10];
    const float* wo    = (const float*)d_in[11];
    const float* bo    = (const float*)d_in[12];
    const int*   nk    = (const int*)d_in[13];

    char* ws = (char*)d_ws;
    unsigned short* wqt = (unsigned short*)(ws + 0);          // 128 KB
    unsigned short* wkt = (unsigned short*)(ws + 131072);     // 32 KB
    unsigned short* wvt = (unsigned short*)(ws + 163840);     // 32 KB
    unsigned short* wot = (unsigned short*)(ws + 196608);     // 128 KB
    unsigned short* qr  = (unsigned short*)(ws + 327680);     // 2 MB (dead after flash)
    unsigned short* xb  = (unsigned short*)(ws + 327680);     // aliases qr
    unsigned short* krw = (unsigned short*)(ws + 2424832);    // 8.42 MB
    unsigned short* vtg = (unsigned short*)(ws + 10846208);   // 8.42 MB
    half_t* Opart = (half_t*)(ws + 19267584);                 // 16.78 MB (8 splits, fp16)
    float* Mpart = (float*)(ws + 36044800);                   // 128 KB
    float* Lpart = (float*)(ws + 36175872);                   // 128 KB
    float* outp  = (float*)d_out;

    wtrans_kernel<<<dim3(640), dim3(256), 0, stream>>>(wq, wk, wv, wo, wqt, wkt, wvt, wot);
    qproj_kernel<<<dim3(64, 4), dim3(256), 0, stream>>>(query, wqt, bq, cosb, sinb, qr);
    kvproj_kernel<<<dim3(257, 2), dim3(256), 0, stream>>>(key, value, wkt, wvt, bk, bv, cosb, sinb, nk, krw, vtg);
    flash_kernel<<<dim3(32, NSPLIT), dim3(512), 0, stream>>>(qr, krw, vtg, Opart, Mpart, Lpart);
    combine_kernel<<<dim3(512), dim3(256), 0, stream>>>(Opart, Mpart, Lpart, xb);
    oproj_kernel<<<dim3(64, 4), dim3(256), 0, stream>>>(xb, wot, bo, outp);
}